// Round 3
// baseline (593.664 us; speedup 1.0000x reference)
//
#include <hip/hip_runtime.h>

#define NN 50000
#define EE 600000
#define HH 128
#define GG 64
#define NPAD 50176  // 50000 rounded up to multiple of 256

typedef __attribute__((ext_vector_type(8))) short short8;
typedef __attribute__((ext_vector_type(4))) float f32x4;
typedef __attribute__((ext_vector_type(2))) float f32x2;

__device__ __forceinline__ unsigned short f2bf(float f) {
    union { float f; unsigned int i; } v; v.f = f;
    unsigned int u = v.i;
    return (unsigned short)((u + 0x7FFFu + ((u >> 16) & 1u)) >> 16);
}

__device__ __forceinline__ short8 cvt8(f32x4 lo, f32x4 hi) {
    short8 r;
    r[0] = (short)f2bf(lo[0]); r[1] = (short)f2bf(lo[1]);
    r[2] = (short)f2bf(lo[2]); r[3] = (short)f2bf(lo[3]);
    r[4] = (short)f2bf(hi[0]); r[5] = (short)f2bf(hi[1]);
    r[6] = (short)f2bf(hi[2]); r[7] = (short)f2bf(hi[3]);
    return r;
}

// ---------------- CSR build ----------------

__global__ void k_deg(const int* __restrict__ ei, const int* __restrict__ mask,
                      int* __restrict__ deg1, int* __restrict__ deg2, int* __restrict__ deg3) {
    int e = blockIdx.x * 256 + threadIdx.x;
    if (e >= EE) return;
    int d = ei[EE + e];
    int m = mask[e];
    atomicAdd(&deg1[d], 1);
    if (m == 1) atomicAdd(&deg2[d], 1);
    if (m == 2) atomicAdd(&deg3[d], 1);
}

// in-place int deg -> float rsqrt(deg+1)
__global__ void k_dinv(int* __restrict__ deg1, int* __restrict__ deg2, int* __restrict__ deg3) {
    int i = blockIdx.x * 256 + threadIdx.x;
    if (i >= NN) return;
    int a = deg1[i], b = deg2[i], c = deg3[i];
    ((float*)deg1)[i] = rsqrtf((float)a + 1.0f);
    ((float*)deg2)[i] = rsqrtf((float)b + 1.0f);
    ((float*)deg3)[i] = rsqrtf((float)c + 1.0f);
}

// single-block exclusive scan of deg1 -> row_ptr, cursor
__global__ void k_scan(const int* __restrict__ deg, int* __restrict__ rp, int* __restrict__ cur) {
    __shared__ int wsum[16];
    __shared__ int carry_s;
    int t = threadIdx.x, lane = t & 63, w = t >> 6;
    if (t == 0) carry_s = 0;
    __syncthreads();
    for (int base = 0; base < NN; base += 1024) {
        int i = base + t;
        int v = (i < NN) ? deg[i] : 0;
        int x = v;
        #pragma unroll
        for (int off = 1; off < 64; off <<= 1) {
            int u = __shfl_up(x, off);
            if (lane >= off) x += u;
        }
        if (lane == 63) wsum[w] = x;
        __syncthreads();
        int wo = 0;
        for (int k = 0; k < w; k++) wo += wsum[k];
        int excl = carry_s + wo + x - v;
        if (i < NN) { rp[i] = excl; cur[i] = excl; }
        __syncthreads();
        if (t == 1023) carry_s = excl + v;  // running total
        __syncthreads();
    }
    if (threadIdx.x == 0) rp[NN] = carry_s;
}

__global__ void k_fill(const int* __restrict__ ei, const int* __restrict__ mask,
                       int* __restrict__ cur, unsigned int* __restrict__ csr) {
    int e = blockIdx.x * 256 + threadIdx.x;
    if (e >= EE) return;
    int s = ei[e];
    int d = ei[EE + e];
    unsigned int m = (unsigned int)mask[e];
    int slot = atomicAdd(&cur[d], 1);
    csr[slot] = (unsigned int)s | (m << 16);
}

// ---------------- weights transpose+cvt: wt[n][k] = bf16(w[k][n]) ----------------
__global__ void k_wt(const float* __restrict__ w, unsigned short* __restrict__ wt) {
    int i = blockIdx.x * 256 + threadIdx.x;  // 0..16383
    int k = i >> 7, n = i & 127;
    wt[n * HH + k] = f2bf(w[i]);
}

// ---------------- GEMM: h = in @ W  (in: N x 128 f32; wt = bf16 W^T; h f32) ----------------
__global__ __launch_bounds__(256) void k_gemm(const float* __restrict__ in,
                                              const unsigned short* __restrict__ wt,
                                              float* __restrict__ h) {
    int w = threadIdx.x >> 6, lane = threadIdx.x & 63;
    int lr = lane & 15, lg = lane >> 4;
    int rowbase = (blockIdx.x * 4 + w) * 16;
    if (rowbase >= NN) return;
    int arow = rowbase + lr;                 // NN % 16 == 0, always < NN
    const f32x4* ap = (const f32x4*)(in + (size_t)arow * HH + lg * 8);
    short8 a0 = cvt8(ap[0], ap[1]);          // k = lg*8 + 0..7
    short8 a1 = cvt8(ap[8], ap[9]);          // +32
    short8 a2 = cvt8(ap[16], ap[17]);        // +64
    short8 a3 = cvt8(ap[24], ap[25]);        // +96
    f32x4 acc[8];
    #pragma unroll
    for (int i = 0; i < 8; i++) acc[i] = (f32x4){0.f, 0.f, 0.f, 0.f};
    const unsigned short* wbase = wt + lr * HH + lg * 8;
    #pragma unroll
    for (int nc = 0; nc < 8; nc++) {
        const short8* bp = (const short8*)(wbase + nc * 16 * HH);
        short8 b0 = bp[0], b1 = bp[4], b2 = bp[8], b3 = bp[12];
        acc[nc] = __builtin_amdgcn_mfma_f32_16x16x32_bf16(a0, b0, acc[nc], 0, 0, 0);
        acc[nc] = __builtin_amdgcn_mfma_f32_16x16x32_bf16(a1, b1, acc[nc], 0, 0, 0);
        acc[nc] = __builtin_amdgcn_mfma_f32_16x16x32_bf16(a2, b2, acc[nc], 0, 0, 0);
        acc[nc] = __builtin_amdgcn_mfma_f32_16x16x32_bf16(a3, b3, acc[nc], 0, 0, 0);
    }
    int orow = rowbase + lg * 4;
    #pragma unroll
    for (int nc = 0; nc < 8; nc++) {
        #pragma unroll
        for (int j = 0; j < 4; j++) {
            h[(size_t)(orow + j) * HH + nc * 16 + lr] = acc[nc][j];
        }
    }
}

// ---------------- aggregation: g[n] = bias + dinv^2*h[n] + sum_e w_e*h[src_e], optional relu ----------------
__global__ __launch_bounds__(256) void k_agg(const float* __restrict__ h,
                                             const float* __restrict__ dinv,
                                             const unsigned int* __restrict__ csr,
                                             const int* __restrict__ rp,
                                             const float* __restrict__ bias,
                                             float* __restrict__ g,
                                             int sel, int relu) {
    int n = blockIdx.x * 4 + (threadIdx.x >> 6);
    if (n >= NN) return;
    int lane = threadIdx.x & 63;
    int f0 = lane * 2;
    float di = dinv[n];
    float c = di * di;
    f32x2 hp = *(const f32x2*)(h + (size_t)n * HH + f0);
    float acc0 = hp[0] * c;
    float acc1 = hp[1] * c;
    int beg = rp[n], end = rp[n + 1];
    for (int e = beg; e < end; e++) {
        unsigned int p = csr[e];
        int m = (int)(p >> 16);
        if (sel == 0 || m == sel) {
            int s = (int)(p & 0xffffu);
            float wv = dinv[s] * di;
            f32x2 hv = *(const f32x2*)(h + (size_t)s * HH + f0);
            acc0 += wv * hv[0];
            acc1 += wv * hv[1];
        }
    }
    f32x2 bp = *(const f32x2*)(bias + f0);
    acc0 += bp[0];
    acc1 += bp[1];
    if (relu) { acc0 = fmaxf(acc0, 0.f); acc1 = fmaxf(acc1, 0.f); }
    f32x2 o; o[0] = acc0; o[1] = acc1;
    *(f32x2*)(g + (size_t)n * HH + f0) = o;
}

// ---------------- pool + head: out[g] = mean_n(h3[n]) . Wl + bl ----------------
__device__ __forceinline__ int lbound(const int* a, int n, int key) {
    int lo = 0, hi = n;
    while (lo < hi) { int mid = (lo + hi) >> 1; if (a[mid] < key) lo = mid + 1; else hi = mid; }
    return lo;
}

__global__ __launch_bounds__(128) void k_pool(const float* __restrict__ g3,
                                              const int* __restrict__ batch,
                                              const float* __restrict__ Wl,
                                              const float* __restrict__ bl,
                                              float* __restrict__ out) {
    int gid = blockIdx.x;
    int t = threadIdx.x;
    int lo = lbound(batch, NN, gid);
    int hi = lbound(batch, NN, gid + 1);
    float s = 0.f;
    for (int n = lo; n < hi; n++) s += g3[(size_t)n * HH + t];
    float cnt = (float)(hi - lo);
    if (cnt < 1.f) cnt = 1.f;
    float prod = (s / cnt) * Wl[t];
    __shared__ float sm[128];
    sm[t] = prod;
    __syncthreads();
    for (int off = 64; off > 0; off >>= 1) {
        if (t < off) sm[t] += sm[t + off];
        __syncthreads();
    }
    if (t == 0) out[gid] = sm[0] + bl[0];
}

// ---------------- launcher ----------------
extern "C" void kernel_launch(void* const* d_in, const int* in_sizes, int n_in,
                              void* d_out, int out_size, void* d_ws, size_t ws_size,
                              hipStream_t stream) {
    const float* x    = (const float*)d_in[0];
    const int*   ei   = (const int*)d_in[1];
    const int*   mask = (const int*)d_in[2];
    const int*   batch= (const int*)d_in[3];
    const float* W1   = (const float*)d_in[4];
    const float* b1   = (const float*)d_in[5];
    const float* W2   = (const float*)d_in[6];
    const float* b2   = (const float*)d_in[7];
    const float* W3   = (const float*)d_in[8];
    const float* b3   = (const float*)d_in[9];
    const float* Wl   = (const float*)d_in[10];
    const float* bl   = (const float*)d_in[11];
    float* out = (float*)d_out;

    char* ws = (char*)d_ws;
    float* g = (float*)(ws + 0);                           // N*128 f32 = 25,600,000
    float* h = (float*)(ws + 25600000);                    // N*128 f32 = 25,600,000
    unsigned short* wt1 = (unsigned short*)(ws + 51200000);// 3 x 128*128 bf16 = 98,304
    unsigned short* wt2 = wt1 + 16384;
    unsigned short* wt3 = wt2 + 16384;
    int* deg1 = (int*)(ws + 51298304);                     // 3 x NPAD int (becomes dinv float in place)
    int* deg2 = deg1 + NPAD;
    int* deg3 = deg2 + NPAD;
    float* dinv1 = (float*)deg1;
    float* dinv2 = (float*)deg2;
    float* dinv3 = (float*)deg3;
    int* rp  = (int*)(ws + 51900416);                      // NPAD ints (need N+1)
    int* cur = (int*)(ws + 52101120);                      // NPAD ints
    unsigned int* csr = (unsigned int*)(ws + 52301824);    // E uints = 2,400,000
    // total = 54,701,824 bytes

    hipMemsetAsync(deg1, 0, (size_t)3 * NPAD * sizeof(int), stream);

    dim3 b256(256);
    k_deg<<<dim3((EE + 255) / 256), b256, 0, stream>>>(ei, mask, deg1, deg2, deg3);
    k_scan<<<dim3(1), dim3(1024), 0, stream>>>(deg1, rp, cur);
    k_dinv<<<dim3((NN + 255) / 256), b256, 0, stream>>>(deg1, deg2, deg3);
    k_fill<<<dim3((EE + 255) / 256), b256, 0, stream>>>(ei, mask, cur, csr);

    k_wt<<<dim3(64), b256, 0, stream>>>(W1, wt1);
    k_wt<<<dim3(64), b256, 0, stream>>>(W2, wt2);
    k_wt<<<dim3(64), b256, 0, stream>>>(W3, wt3);

    dim3 ggrid((NN + 63) / 64);       // 782 blocks, 64 rows each
    dim3 agrid((NN + 3) / 4);         // 12500 blocks, 4 nodes each

    // layer 1: in = x, all edges
    k_gemm<<<ggrid, b256, 0, stream>>>(x, wt1, h);
    k_agg<<<agrid, b256, 0, stream>>>(h, dinv1, csr, rp, b1, g, 0, 1);
    // layer 2: sel = 1
    k_gemm<<<ggrid, b256, 0, stream>>>(g, wt2, h);
    k_agg<<<agrid, b256, 0, stream>>>(h, dinv2, csr, rp, b2, g, 1, 1);
    // layer 3: sel = 2, no relu
    k_gemm<<<ggrid, b256, 0, stream>>>(g, wt3, h);
    k_agg<<<agrid, b256, 0, stream>>>(h, dinv3, csr, rp, b3, g, 2, 0);

    k_pool<<<dim3(GG), dim3(128), 0, stream>>>(g, batch, Wl, bl, out);
}

// Round 4
// 419.660 us; speedup vs baseline: 1.4146x; 1.4146x over previous
//
#include <hip/hip_runtime.h>

#define NN 50000
#define EE 600000
#define HH 128
#define GG 64
#define NPAD 50176  // 50000 rounded up to multiple of 256

typedef __attribute__((ext_vector_type(8))) short short8;
typedef __attribute__((ext_vector_type(4))) float f32x4;
typedef __attribute__((ext_vector_type(2))) float f32x2;

__device__ __forceinline__ unsigned short f2bf(float f) {
    union { float f; unsigned int i; } v; v.f = f;
    unsigned int u = v.i;
    return (unsigned short)((u + 0x7FFFu + ((u >> 16) & 1u)) >> 16);
}

__device__ __forceinline__ short8 cvt8(f32x4 lo, f32x4 hi) {
    short8 r;
    r[0] = (short)f2bf(lo[0]); r[1] = (short)f2bf(lo[1]);
    r[2] = (short)f2bf(lo[2]); r[3] = (short)f2bf(lo[3]);
    r[4] = (short)f2bf(hi[0]); r[5] = (short)f2bf(hi[1]);
    r[6] = (short)f2bf(hi[2]); r[7] = (short)f2bf(hi[3]);
    return r;
}

// ---------------- CSR build ----------------

__global__ void k_deg(const int* __restrict__ ei, const int* __restrict__ mask,
                      int* __restrict__ deg1, int* __restrict__ deg2, int* __restrict__ deg3) {
    int e = blockIdx.x * 256 + threadIdx.x;
    if (e >= EE) return;
    int d = ei[EE + e];
    int m = mask[e];
    atomicAdd(&deg1[d], 1);
    if (m == 1) atomicAdd(&deg2[d], 1);
    if (m == 2) atomicAdd(&deg3[d], 1);
}

// in-place int deg -> float rsqrt(deg+1)
__global__ void k_dinv(int* __restrict__ deg1, int* __restrict__ deg2, int* __restrict__ deg3) {
    int i = blockIdx.x * 256 + threadIdx.x;
    if (i >= NN) return;
    int a = deg1[i], b = deg2[i], c = deg3[i];
    ((float*)deg1)[i] = rsqrtf((float)a + 1.0f);
    ((float*)deg2)[i] = rsqrtf((float)b + 1.0f);
    ((float*)deg3)[i] = rsqrtf((float)c + 1.0f);
}

// single-block exclusive scan of deg1 -> row_ptr, cursor
__global__ void k_scan(const int* __restrict__ deg, int* __restrict__ rp, int* __restrict__ cur) {
    __shared__ int wsum[16];
    __shared__ int carry_s;
    int t = threadIdx.x, lane = t & 63, w = t >> 6;
    if (t == 0) carry_s = 0;
    __syncthreads();
    for (int base = 0; base < NN; base += 1024) {
        int i = base + t;
        int v = (i < NN) ? deg[i] : 0;
        int x = v;
        #pragma unroll
        for (int off = 1; off < 64; off <<= 1) {
            int u = __shfl_up(x, off);
            if (lane >= off) x += u;
        }
        if (lane == 63) wsum[w] = x;
        __syncthreads();
        int wo = 0;
        for (int k = 0; k < w; k++) wo += wsum[k];
        int excl = carry_s + wo + x - v;
        if (i < NN) { rp[i] = excl; cur[i] = excl; }
        __syncthreads();
        if (t == 1023) carry_s = excl + v;  // running total
        __syncthreads();
    }
    if (threadIdx.x == 0) rp[NN] = carry_s;
}

__global__ void k_fill(const int* __restrict__ ei, const int* __restrict__ mask,
                       int* __restrict__ cur, unsigned int* __restrict__ csr) {
    int e = blockIdx.x * 256 + threadIdx.x;
    if (e >= EE) return;
    int s = ei[e];
    int d = ei[EE + e];
    unsigned int m = (unsigned int)mask[e];
    int slot = atomicAdd(&cur[d], 1);
    csr[slot] = (unsigned int)s | (m << 16);
}

// ---------------- weights transpose+cvt: wt[n][k] = bf16(w[k][n]) ----------------
__global__ void k_wt(const float* __restrict__ w, unsigned short* __restrict__ wt) {
    int i = blockIdx.x * 256 + threadIdx.x;  // 0..16383
    int k = i >> 7, n = i & 127;
    wt[n * HH + k] = f2bf(w[i]);
}

// ---------------- GEMM: h = in @ W  (in: N x 128 f32; wt = bf16 W^T; h f32) ----------------
__global__ __launch_bounds__(256) void k_gemm(const float* __restrict__ in,
                                              const unsigned short* __restrict__ wt,
                                              float* __restrict__ h) {
    int w = threadIdx.x >> 6, lane = threadIdx.x & 63;
    int lr = lane & 15, lg = lane >> 4;
    int rowbase = (blockIdx.x * 4 + w) * 16;
    if (rowbase >= NN) return;
    int arow = rowbase + lr;                 // NN % 16 == 0, always < NN
    const f32x4* ap = (const f32x4*)(in + (size_t)arow * HH + lg * 8);
    short8 a0 = cvt8(ap[0], ap[1]);          // k = lg*8 + 0..7
    short8 a1 = cvt8(ap[8], ap[9]);          // +32
    short8 a2 = cvt8(ap[16], ap[17]);        // +64
    short8 a3 = cvt8(ap[24], ap[25]);        // +96
    f32x4 acc[8];
    #pragma unroll
    for (int i = 0; i < 8; i++) acc[i] = (f32x4){0.f, 0.f, 0.f, 0.f};
    const unsigned short* wbase = wt + lr * HH + lg * 8;
    #pragma unroll
    for (int nc = 0; nc < 8; nc++) {
        const short8* bp = (const short8*)(wbase + nc * 16 * HH);
        short8 b0 = bp[0], b1 = bp[4], b2 = bp[8], b3 = bp[12];
        acc[nc] = __builtin_amdgcn_mfma_f32_16x16x32_bf16(a0, b0, acc[nc], 0, 0, 0);
        acc[nc] = __builtin_amdgcn_mfma_f32_16x16x32_bf16(a1, b1, acc[nc], 0, 0, 0);
        acc[nc] = __builtin_amdgcn_mfma_f32_16x16x32_bf16(a2, b2, acc[nc], 0, 0, 0);
        acc[nc] = __builtin_amdgcn_mfma_f32_16x16x32_bf16(a3, b3, acc[nc], 0, 0, 0);
    }
    int orow = rowbase + lg * 4;
    #pragma unroll
    for (int nc = 0; nc < 8; nc++) {
        #pragma unroll
        for (int j = 0; j < 4; j++) {
            h[(size_t)(orow + j) * HH + nc * 16 + lr] = acc[nc][j];
        }
    }
}

// ---------------- aggregation: g[n] = bias + dinv^2*h[n] + sum_e w_e*h[src_e], optional relu ----------------
__global__ __launch_bounds__(256) void k_agg(const float* __restrict__ h,
                                             const float* __restrict__ dinv,
                                             const unsigned int* __restrict__ csr,
                                             const int* __restrict__ rp,
                                             const float* __restrict__ bias,
                                             float* __restrict__ g,
                                             int sel, int relu) {
    int n = blockIdx.x * 4 + (threadIdx.x >> 6);
    if (n >= NN) return;
    int lane = threadIdx.x & 63;
    int f0 = lane * 2;
    float di = dinv[n];
    float c = di * di;
    f32x2 hp = *(const f32x2*)(h + (size_t)n * HH + f0);
    float acc0 = hp[0] * c;
    float acc1 = hp[1] * c;
    int beg = rp[n], end = rp[n + 1];
    for (int e = beg; e < end; e++) {
        unsigned int p = csr[e];
        int m = (int)(p >> 16);
        if (sel == 0 || m == sel) {
            int s = (int)(p & 0xffffu);
            float wv = dinv[s] * di;
            f32x2 hv = *(const f32x2*)(h + (size_t)s * HH + f0);
            acc0 += wv * hv[0];
            acc1 += wv * hv[1];
        }
    }
    f32x2 bp = *(const f32x2*)(bias + f0);
    acc0 += bp[0];
    acc1 += bp[1];
    if (relu) { acc0 = fmaxf(acc0, 0.f); acc1 = fmaxf(acc1, 0.f); }
    f32x2 o; o[0] = acc0; o[1] = acc1;
    *(f32x2*)(g + (size_t)n * HH + f0) = o;
}

// ---------------- pool stage 1: per-block partial sums -> atomicAdd into sums[G][128] ----------------
__global__ __launch_bounds__(128) void k_pool_part(const float* __restrict__ g3,
                                                   const int* __restrict__ batch,
                                                   float* __restrict__ sums) {
    int t = threadIdx.x;            // feature
    int n0 = blockIdx.x * 64;
    int n1 = n0 + 64; if (n1 > NN) n1 = NN;
    if (n0 >= NN) return;
    int curb = batch[n0];
    float acc = 0.f;
    for (int n = n0; n < n1; n++) {
        int b = batch[n];
        if (b != curb) {
            atomicAdd(&sums[curb * HH + t], acc);
            acc = 0.f;
            curb = b;
        }
        acc += g3[(size_t)n * HH + t];
    }
    atomicAdd(&sums[curb * HH + t], acc);
}

// ---------------- pool stage 2 + head ----------------
__device__ __forceinline__ int lbound(const int* a, int n, int key) {
    int lo = 0, hi = n;
    while (lo < hi) { int mid = (lo + hi) >> 1; if (a[mid] < key) lo = mid + 1; else hi = mid; }
    return lo;
}

__global__ __launch_bounds__(128) void k_head(const float* __restrict__ sums,
                                              const int* __restrict__ batch,
                                              const float* __restrict__ Wl,
                                              const float* __restrict__ bl,
                                              float* __restrict__ out) {
    int gid = blockIdx.x;
    int t = threadIdx.x;
    int lo = lbound(batch, NN, gid);
    int hi = lbound(batch, NN, gid + 1);
    float cnt = (float)(hi - lo);
    if (cnt < 1.f) cnt = 1.f;
    float prod = (sums[gid * HH + t] / cnt) * Wl[t];
    __shared__ float sm[128];
    sm[t] = prod;
    __syncthreads();
    for (int off = 64; off > 0; off >>= 1) {
        if (t < off) sm[t] += sm[t + off];
        __syncthreads();
    }
    if (t == 0) out[gid] = sm[0] + bl[0];
}

// ---------------- launcher ----------------
extern "C" void kernel_launch(void* const* d_in, const int* in_sizes, int n_in,
                              void* d_out, int out_size, void* d_ws, size_t ws_size,
                              hipStream_t stream) {
    const float* x    = (const float*)d_in[0];
    const int*   ei   = (const int*)d_in[1];
    const int*   mask = (const int*)d_in[2];
    const int*   batch= (const int*)d_in[3];
    const float* W1   = (const float*)d_in[4];
    const float* b1   = (const float*)d_in[5];
    const float* W2   = (const float*)d_in[6];
    const float* b2   = (const float*)d_in[7];
    const float* W3   = (const float*)d_in[8];
    const float* b3   = (const float*)d_in[9];
    const float* Wl   = (const float*)d_in[10];
    const float* bl   = (const float*)d_in[11];
    float* out = (float*)d_out;

    char* ws = (char*)d_ws;
    float* g = (float*)(ws + 0);                           // N*128 f32 = 25,600,000
    float* h = (float*)(ws + 25600000);                    // N*128 f32 = 25,600,000
    unsigned short* wt1 = (unsigned short*)(ws + 51200000);// 3 x 128*128 bf16 = 98,304
    unsigned short* wt2 = wt1 + 16384;
    unsigned short* wt3 = wt2 + 16384;
    int* deg1 = (int*)(ws + 51298304);                     // 3 x NPAD int (becomes dinv float in place)
    int* deg2 = deg1 + NPAD;
    int* deg3 = deg2 + NPAD;
    float* dinv1 = (float*)deg1;
    float* dinv2 = (float*)deg2;
    float* dinv3 = (float*)deg3;
    int* rp  = (int*)(ws + 51900416);                      // NPAD ints (need N+1)
    int* cur = (int*)(ws + 52101120);                      // NPAD ints; reused as sums[G*128] f32 after k_fill
    unsigned int* csr = (unsigned int*)(ws + 52301824);    // E uints = 2,400,000
    float* sums = (float*)cur;                             // 64*128 f32 = 32,768 bytes (< NPAD*4)
    // total = 54,701,824 bytes

    hipMemsetAsync(deg1, 0, (size_t)3 * NPAD * sizeof(int), stream);

    dim3 b256(256);
    k_deg<<<dim3((EE + 255) / 256), b256, 0, stream>>>(ei, mask, deg1, deg2, deg3);
    k_scan<<<dim3(1), dim3(1024), 0, stream>>>(deg1, rp, cur);
    k_dinv<<<dim3((NN + 255) / 256), b256, 0, stream>>>(deg1, deg2, deg3);
    k_fill<<<dim3((EE + 255) / 256), b256, 0, stream>>>(ei, mask, cur, csr);
    // cur is dead from here on; reuse as pooled sums
    hipMemsetAsync(sums, 0, (size_t)GG * HH * sizeof(float), stream);

    k_wt<<<dim3(64), b256, 0, stream>>>(W1, wt1);
    k_wt<<<dim3(64), b256, 0, stream>>>(W2, wt2);
    k_wt<<<dim3(64), b256, 0, stream>>>(W3, wt3);

    dim3 ggrid((NN + 63) / 64);       // 782 blocks, 64 rows each
    dim3 agrid((NN + 3) / 4);         // 12500 blocks, 4 nodes each

    // layer 1: in = x, all edges
    k_gemm<<<ggrid, b256, 0, stream>>>(x, wt1, h);
    k_agg<<<agrid, b256, 0, stream>>>(h, dinv1, csr, rp, b1, g, 0, 1);
    // layer 2: sel = 1
    k_gemm<<<ggrid, b256, 0, stream>>>(g, wt2, h);
    k_agg<<<agrid, b256, 0, stream>>>(h, dinv2, csr, rp, b2, g, 1, 1);
    // layer 3: sel = 2, no relu
    k_gemm<<<ggrid, b256, 0, stream>>>(g, wt3, h);
    k_agg<<<agrid, b256, 0, stream>>>(h, dinv3, csr, rp, b3, g, 2, 0);

    k_pool_part<<<dim3((NN + 63) / 64), dim3(128), 0, stream>>>(g, batch, sums);
    k_head<<<dim3(GG), dim3(128), 0, stream>>>(sums, batch, Wl, bl, out);
}

// Round 5
// 353.605 us; speedup vs baseline: 1.6789x; 1.1868x over previous
//
#include <hip/hip_runtime.h>

#define NN 50000
#define EE 600000
#define HH 128
#define GG 64
#define NPAD 50176  // 50000 rounded up to multiple of 256
#define NBLK 196    // NPAD / 256

typedef __attribute__((ext_vector_type(8))) short short8;
typedef __attribute__((ext_vector_type(4))) float f32x4;
typedef __attribute__((ext_vector_type(2))) float f32x2;

__device__ __forceinline__ float bf2f(unsigned int u16) {
    union { unsigned int i; float f; } v; v.i = u16 << 16; return v.f;
}
__device__ __forceinline__ unsigned short f2bf(float f) {
    union { float f; unsigned int i; } v; v.f = f;
    unsigned int u = v.i;
    return (unsigned short)((u + 0x7FFFu + ((u >> 16) & 1u)) >> 16);
}

__device__ __forceinline__ short8 cvt8(f32x4 lo, f32x4 hi) {
    short8 r;
    r[0] = (short)f2bf(lo[0]); r[1] = (short)f2bf(lo[1]);
    r[2] = (short)f2bf(lo[2]); r[3] = (short)f2bf(lo[3]);
    r[4] = (short)f2bf(hi[0]); r[5] = (short)f2bf(hi[1]);
    r[6] = (short)f2bf(hi[2]); r[7] = (short)f2bf(hi[3]);
    return r;
}

// ---------------- CSR build ----------------

__global__ void k_deg(const int* __restrict__ ei, const int* __restrict__ mask,
                      int* __restrict__ deg1, int* __restrict__ deg2, int* __restrict__ deg3) {
    int e = blockIdx.x * 256 + threadIdx.x;
    if (e >= EE) return;
    int d = ei[EE + e];
    int m = mask[e];
    atomicAdd(&deg1[d], 1);
    if (m == 1) atomicAdd(&deg2[d], 1);
    if (m == 2) atomicAdd(&deg3[d], 1);
}

// in-place int deg -> float rsqrt(deg+1)
__global__ void k_dinv(int* __restrict__ deg1, int* __restrict__ deg2, int* __restrict__ deg3) {
    int i = blockIdx.x * 256 + threadIdx.x;
    if (i >= NN) return;
    int a = deg1[i], b = deg2[i], c = deg3[i];
    ((float*)deg1)[i] = rsqrtf((float)a + 1.0f);
    ((float*)deg2)[i] = rsqrtf((float)b + 1.0f);
    ((float*)deg3)[i] = rsqrtf((float)c + 1.0f);
}

// ---------------- hierarchical scan: deg -> rp (exclusive), cur ----------------
// stage 1: per-block (256) sums
__global__ __launch_bounds__(256) void k_scan1(const int* __restrict__ deg, int* __restrict__ btot) {
    __shared__ int ws[4];
    int t = threadIdx.x, lane = t & 63, w = t >> 6;
    int v = deg[blockIdx.x * 256 + t];
    #pragma unroll
    for (int off = 32; off > 0; off >>= 1) v += __shfl_xor(v, off);
    if (lane == 0) ws[w] = v;
    __syncthreads();
    if (t == 0) btot[blockIdx.x] = ws[0] + ws[1] + ws[2] + ws[3];
}

// stage 2: single block scans NBLK block totals -> exclusive offsets
__global__ __launch_bounds__(256) void k_scan2(const int* __restrict__ btot, int* __restrict__ boff) {
    __shared__ int ws[4];
    int t = threadIdx.x, lane = t & 63, w = t >> 6;
    int v = (t < NBLK) ? btot[t] : 0;
    int x = v;
    #pragma unroll
    for (int off = 1; off < 64; off <<= 1) {
        int u = __shfl_up(x, off);
        if (lane >= off) x += u;
    }
    if (lane == 63) ws[w] = x;
    __syncthreads();
    int wo = 0;
    for (int k = 0; k < w; k++) wo += ws[k];
    if (t < NBLK) boff[t] = wo + x - v;
}

// stage 3: per-block scan + offset -> rp, cur (covers i up to NPAD-1; rp[NN] lands naturally)
__global__ __launch_bounds__(256) void k_scan3(const int* __restrict__ deg, const int* __restrict__ boff,
                                               int* __restrict__ rp, int* __restrict__ cur) {
    __shared__ int ws[4];
    int t = threadIdx.x, lane = t & 63, w = t >> 6;
    int i = blockIdx.x * 256 + t;
    int v = deg[i];
    int x = v;
    #pragma unroll
    for (int off = 1; off < 64; off <<= 1) {
        int u = __shfl_up(x, off);
        if (lane >= off) x += u;
    }
    if (lane == 63) ws[w] = x;
    __syncthreads();
    int wo = 0;
    for (int k = 0; k < w; k++) wo += ws[k];
    int r = boff[blockIdx.x] + wo + x - v;
    rp[i] = r;
    cur[i] = r;
}

__global__ void k_fill(const int* __restrict__ ei, const int* __restrict__ mask,
                       int* __restrict__ cur, unsigned int* __restrict__ csr) {
    int e = blockIdx.x * 256 + threadIdx.x;
    if (e >= EE) return;
    int s = ei[e];
    int d = ei[EE + e];
    unsigned int m = (unsigned int)mask[e];
    int slot = atomicAdd(&cur[d], 1);
    csr[slot] = (unsigned int)s | (m << 16);
}

// ---------------- weights transpose+cvt: wt[n][k] = bf16(w[k][n]) ----------------
__global__ void k_wt(const float* __restrict__ w, unsigned short* __restrict__ wt) {
    int i = blockIdx.x * 256 + threadIdx.x;  // 0..16383
    int k = i >> 7, n = i & 127;
    wt[n * HH + k] = f2bf(w[i]);
}

// ---------------- GEMM: h(bf16) = in(f32) @ W  (wt = bf16 W^T) ----------------
__global__ __launch_bounds__(256) void k_gemm(const float* __restrict__ in,
                                              const unsigned short* __restrict__ wt,
                                              unsigned short* __restrict__ h) {
    int w = threadIdx.x >> 6, lane = threadIdx.x & 63;
    int lr = lane & 15, lg = lane >> 4;
    int rowbase = (blockIdx.x * 4 + w) * 16;
    if (rowbase >= NN) return;
    int arow = rowbase + lr;                 // NN % 16 == 0, always < NN
    const f32x4* ap = (const f32x4*)(in + (size_t)arow * HH + lg * 8);
    short8 a0 = cvt8(ap[0], ap[1]);          // k = lg*8 + 0..7
    short8 a1 = cvt8(ap[8], ap[9]);          // +32
    short8 a2 = cvt8(ap[16], ap[17]);        // +64
    short8 a3 = cvt8(ap[24], ap[25]);        // +96
    f32x4 acc[8];
    #pragma unroll
    for (int i = 0; i < 8; i++) acc[i] = (f32x4){0.f, 0.f, 0.f, 0.f};
    const unsigned short* wbase = wt + lr * HH + lg * 8;
    #pragma unroll
    for (int nc = 0; nc < 8; nc++) {
        const short8* bp = (const short8*)(wbase + nc * 16 * HH);
        short8 b0 = bp[0], b1 = bp[4], b2 = bp[8], b3 = bp[12];
        acc[nc] = __builtin_amdgcn_mfma_f32_16x16x32_bf16(a0, b0, acc[nc], 0, 0, 0);
        acc[nc] = __builtin_amdgcn_mfma_f32_16x16x32_bf16(a1, b1, acc[nc], 0, 0, 0);
        acc[nc] = __builtin_amdgcn_mfma_f32_16x16x32_bf16(a2, b2, acc[nc], 0, 0, 0);
        acc[nc] = __builtin_amdgcn_mfma_f32_16x16x32_bf16(a3, b3, acc[nc], 0, 0, 0);
    }
    int orow = rowbase + lg * 4;
    #pragma unroll
    for (int nc = 0; nc < 8; nc++) {
        #pragma unroll
        for (int j = 0; j < 4; j++) {
            h[(size_t)(orow + j) * HH + nc * 16 + lr] = f2bf(acc[nc][j]);
        }
    }
}

// ---------------- aggregation: g[n](f32) = bias + dinv^2*h[n] + sum_e w_e*h[src_e] ----------------
__global__ __launch_bounds__(256) void k_agg(const unsigned short* __restrict__ h,
                                             const float* __restrict__ dinv,
                                             const unsigned int* __restrict__ csr,
                                             const int* __restrict__ rp,
                                             const float* __restrict__ bias,
                                             float* __restrict__ g,
                                             int sel, int relu) {
    int n = blockIdx.x * 4 + (threadIdx.x >> 6);
    if (n >= NN) return;
    int lane = threadIdx.x & 63;
    int f0 = lane * 2;
    float di = dinv[n];
    float c = di * di;
    unsigned int hp = *(const unsigned int*)(h + (size_t)n * HH + f0);
    float acc0 = bf2f(hp & 0xffffu) * c;
    float acc1 = bf2f(hp >> 16) * c;
    int beg = rp[n], end = rp[n + 1];
    for (int e = beg; e < end; e++) {
        unsigned int p = csr[e];
        int m = (int)(p >> 16);
        if (sel == 0 || m == sel) {
            int s = (int)(p & 0xffffu);
            float wv = dinv[s] * di;
            unsigned int hv = *(const unsigned int*)(h + (size_t)s * HH + f0);
            acc0 += wv * bf2f(hv & 0xffffu);
            acc1 += wv * bf2f(hv >> 16);
        }
    }
    f32x2 bp = *(const f32x2*)(bias + f0);
    acc0 += bp[0];
    acc1 += bp[1];
    if (relu) { acc0 = fmaxf(acc0, 0.f); acc1 = fmaxf(acc1, 0.f); }
    f32x2 o; o[0] = acc0; o[1] = acc1;
    *(f32x2*)(g + (size_t)n * HH + f0) = o;
}

// ---------------- pool stage 1: per-block partial sums -> atomicAdd into sums[G][128] ----------------
__global__ __launch_bounds__(128) void k_pool_part(const float* __restrict__ g3,
                                                   const int* __restrict__ batch,
                                                   float* __restrict__ sums) {
    int t = threadIdx.x;            // feature
    int n0 = blockIdx.x * 64;
    int n1 = n0 + 64; if (n1 > NN) n1 = NN;
    if (n0 >= NN) return;
    int curb = batch[n0];
    float acc = 0.f;
    for (int n = n0; n < n1; n++) {
        int b = batch[n];
        if (b != curb) {
            atomicAdd(&sums[curb * HH + t], acc);
            acc = 0.f;
            curb = b;
        }
        acc += g3[(size_t)n * HH + t];
    }
    atomicAdd(&sums[curb * HH + t], acc);
}

// ---------------- pool stage 2 + head ----------------
__device__ __forceinline__ int lbound(const int* a, int n, int key) {
    int lo = 0, hi = n;
    while (lo < hi) { int mid = (lo + hi) >> 1; if (a[mid] < key) lo = mid + 1; else hi = mid; }
    return lo;
}

__global__ __launch_bounds__(128) void k_head(const float* __restrict__ sums,
                                              const int* __restrict__ batch,
                                              const float* __restrict__ Wl,
                                              const float* __restrict__ bl,
                                              float* __restrict__ out) {
    int gid = blockIdx.x;
    int t = threadIdx.x;
    int lo = lbound(batch, NN, gid);
    int hi = lbound(batch, NN, gid + 1);
    float cnt = (float)(hi - lo);
    if (cnt < 1.f) cnt = 1.f;
    float prod = (sums[gid * HH + t] / cnt) * Wl[t];
    __shared__ float sm[128];
    sm[t] = prod;
    __syncthreads();
    for (int off = 64; off > 0; off >>= 1) {
        if (t < off) sm[t] += sm[t + off];
        __syncthreads();
    }
    if (t == 0) out[gid] = sm[0] + bl[0];
}

// ---------------- launcher ----------------
extern "C" void kernel_launch(void* const* d_in, const int* in_sizes, int n_in,
                              void* d_out, int out_size, void* d_ws, size_t ws_size,
                              hipStream_t stream) {
    const float* x    = (const float*)d_in[0];
    const int*   ei   = (const int*)d_in[1];
    const int*   mask = (const int*)d_in[2];
    const int*   batch= (const int*)d_in[3];
    const float* W1   = (const float*)d_in[4];
    const float* b1   = (const float*)d_in[5];
    const float* W2   = (const float*)d_in[6];
    const float* b2   = (const float*)d_in[7];
    const float* W3   = (const float*)d_in[8];
    const float* b3   = (const float*)d_in[9];
    const float* Wl   = (const float*)d_in[10];
    const float* bl   = (const float*)d_in[11];
    float* out = (float*)d_out;

    char* ws = (char*)d_ws;
    float* g = (float*)(ws + 0);                           // N*128 f32 = 25,600,000
    unsigned short* h = (unsigned short*)(ws + 25600000);  // N*128 bf16 = 12,800,000
    int* btot = (int*)(ws + 38400000);                     // NBLK ints
    int* boff = (int*)(ws + 38401024);                     // NBLK ints
    unsigned short* wt1 = (unsigned short*)(ws + 51200000);// 3 x 128*128 bf16 = 98,304
    unsigned short* wt2 = wt1 + 16384;
    unsigned short* wt3 = wt2 + 16384;
    int* deg1 = (int*)(ws + 51298304);                     // 3 x NPAD int (becomes dinv float in place)
    int* deg2 = deg1 + NPAD;
    int* deg3 = deg2 + NPAD;
    float* dinv1 = (float*)deg1;
    float* dinv2 = (float*)deg2;
    float* dinv3 = (float*)deg3;
    int* rp  = (int*)(ws + 51900416);                      // NPAD ints (need N+1)
    int* cur = (int*)(ws + 52101120);                      // NPAD ints; reused as sums after k_fill
    unsigned int* csr = (unsigned int*)(ws + 52301824);    // E uints = 2,400,000
    float* sums = (float*)cur;                             // 64*128 f32 = 32,768 bytes
    // total = 54,701,824 bytes

    hipMemsetAsync(deg1, 0, (size_t)3 * NPAD * sizeof(int), stream);

    dim3 b256(256);
    k_deg<<<dim3((EE + 255) / 256), b256, 0, stream>>>(ei, mask, deg1, deg2, deg3);
    k_scan1<<<dim3(NBLK), b256, 0, stream>>>(deg1, btot);
    k_scan2<<<dim3(1), b256, 0, stream>>>(btot, boff);
    k_scan3<<<dim3(NBLK), b256, 0, stream>>>(deg1, boff, rp, cur);
    k_dinv<<<dim3((NN + 255) / 256), b256, 0, stream>>>(deg1, deg2, deg3);
    k_fill<<<dim3((EE + 255) / 256), b256, 0, stream>>>(ei, mask, cur, csr);
    // cur is dead from here on; reuse as pooled sums
    hipMemsetAsync(sums, 0, (size_t)GG * HH * sizeof(float), stream);

    k_wt<<<dim3(64), b256, 0, stream>>>(W1, wt1);
    k_wt<<<dim3(64), b256, 0, stream>>>(W2, wt2);
    k_wt<<<dim3(64), b256, 0, stream>>>(W3, wt3);

    dim3 ggrid((NN + 63) / 64);       // 782 blocks, 64 rows each
    dim3 agrid((NN + 3) / 4);         // 12500 blocks, 4 nodes each

    // layer 1: in = x, all edges
    k_gemm<<<ggrid, b256, 0, stream>>>(x, wt1, h);
    k_agg<<<agrid, b256, 0, stream>>>(h, dinv1, csr, rp, b1, g, 0, 1);
    // layer 2: sel = 1
    k_gemm<<<ggrid, b256, 0, stream>>>(g, wt2, h);
    k_agg<<<agrid, b256, 0, stream>>>(h, dinv2, csr, rp, b2, g, 1, 1);
    // layer 3: sel = 2, no relu
    k_gemm<<<ggrid, b256, 0, stream>>>(g, wt3, h);
    k_agg<<<agrid, b256, 0, stream>>>(h, dinv3, csr, rp, b3, g, 2, 0);

    k_pool_part<<<dim3((NN + 63) / 64), dim3(128), 0, stream>>>(g, batch, sums);
    k_head<<<dim3(GG), dim3(128), 0, stream>>>(sums, batch, Wl, bl, out);
}

// Round 6
// 288.498 us; speedup vs baseline: 2.0578x; 1.2257x over previous
//
#include <hip/hip_runtime.h>

#define NN 50000
#define EE 600000
#define HH 128
#define GG 64
#define NPAD 50176   // 50000 rounded up to multiple of 256
#define NSEC3 150528 // 3 * NPAD
#define NBLK3 588    // NSEC3 / 256

typedef __attribute__((ext_vector_type(8))) short short8;
typedef __attribute__((ext_vector_type(4))) float f32x4;
typedef __attribute__((ext_vector_type(4))) unsigned int u32x4;

__device__ __forceinline__ float bf2f(unsigned int u16) {
    union { unsigned int i; float f; } v; v.i = u16 << 16; return v.f;
}
__device__ __forceinline__ unsigned short f2bf(float f) {
    union { float f; unsigned int i; } v; v.f = f;
    unsigned int u = v.i;
    return (unsigned short)((u + 0x7FFFu + ((u >> 16) & 1u)) >> 16);
}

__device__ __forceinline__ short8 cvt8(f32x4 lo, f32x4 hi) {
    short8 r;
    r[0] = (short)f2bf(lo[0]); r[1] = (short)f2bf(lo[1]);
    r[2] = (short)f2bf(lo[2]); r[3] = (short)f2bf(lo[3]);
    r[4] = (short)f2bf(hi[0]); r[5] = (short)f2bf(hi[1]);
    r[6] = (short)f2bf(hi[2]); r[7] = (short)f2bf(hi[3]);
    return r;
}

// ---------------- degree histograms (3 masks) ----------------
__global__ void k_deg(const int* __restrict__ ei, const int* __restrict__ mask,
                      int* __restrict__ deg) {
    int e = blockIdx.x * 256 + threadIdx.x;
    if (e >= EE) return;
    int d = ei[EE + e];
    int m = mask[e];
    atomicAdd(&deg[d], 1);
    if (m == 1) atomicAdd(&deg[NPAD + d], 1);
    if (m == 2) atomicAdd(&deg[2 * NPAD + d], 1);
}

// in-place: int deg -> float rsqrt(deg+1), all 3 sections
__global__ void k_dinv(int* __restrict__ deg) {
    int i = blockIdx.x * 256 + threadIdx.x;
    if (i >= NN) return;
    int a = deg[i], b = deg[NPAD + i], c = deg[2 * NPAD + i];
    ((float*)deg)[i] = rsqrtf((float)a + 1.0f);
    ((float*)deg)[NPAD + i] = rsqrtf((float)b + 1.0f);
    ((float*)deg)[2 * NPAD + i] = rsqrtf((float)c + 1.0f);
}

// ---------------- hierarchical scan over concatenated deg (3*NPAD) ----------------
__global__ __launch_bounds__(256) void k_scan1(const int* __restrict__ deg, int* __restrict__ btot) {
    __shared__ int ws[4];
    int t = threadIdx.x, lane = t & 63, w = t >> 6;
    int v = deg[blockIdx.x * 256 + t];
    #pragma unroll
    for (int off = 32; off > 0; off >>= 1) v += __shfl_xor(v, off);
    if (lane == 0) ws[w] = v;
    __syncthreads();
    if (t == 0) btot[blockIdx.x] = ws[0] + ws[1] + ws[2] + ws[3];
}

__global__ __launch_bounds__(1024) void k_scan2(const int* __restrict__ btot, int* __restrict__ boff) {
    __shared__ int ws[16];
    int t = threadIdx.x, lane = t & 63, w = t >> 6;
    int v = (t < NBLK3) ? btot[t] : 0;
    int x = v;
    #pragma unroll
    for (int off = 1; off < 64; off <<= 1) {
        int u = __shfl_up(x, off);
        if (lane >= off) x += u;
    }
    if (lane == 63) ws[w] = x;
    __syncthreads();
    int wo = 0;
    for (int k = 0; k < w; k++) wo += ws[k];
    if (t < NBLK3) boff[t] = wo + x - v;
}

__global__ __launch_bounds__(256) void k_scan3(const int* __restrict__ deg, const int* __restrict__ boff,
                                               int* __restrict__ rp, int* __restrict__ cur) {
    __shared__ int ws[4];
    int t = threadIdx.x, lane = t & 63, w = t >> 6;
    int i = blockIdx.x * 256 + t;
    int v = deg[i];
    int x = v;
    #pragma unroll
    for (int off = 1; off < 64; off <<= 1) {
        int u = __shfl_up(x, off);
        if (lane >= off) x += u;
    }
    if (lane == 63) ws[w] = x;
    __syncthreads();
    int wo = 0;
    for (int k = 0; k < w; k++) wo += ws[k];
    int r = boff[blockIdx.x] + wo + x - v;
    rp[i] = r;
    cur[i] = r;
}

// ---------------- fill all 3 CSR sections (global slot indices) ----------------
__global__ void k_fill3(const int* __restrict__ ei, const int* __restrict__ mask,
                        int* __restrict__ cur, unsigned int* __restrict__ csr) {
    int e = blockIdx.x * 256 + threadIdx.x;
    if (e >= EE) return;
    int s = ei[e];
    int d = ei[EE + e];
    int m = mask[e];
    int slot = atomicAdd(&cur[d], 1);
    csr[slot] = (unsigned int)s;
    if (m == 1) { slot = atomicAdd(&cur[NPAD + d], 1); csr[slot] = (unsigned int)s; }
    if (m == 2) { slot = atomicAdd(&cur[2 * NPAD + d], 1); csr[slot] = (unsigned int)s; }
}

// ---------------- weights transpose+cvt: wt[n][k] = bf16(w[k][n]) ----------------
__global__ void k_wt(const float* __restrict__ w, unsigned short* __restrict__ wt) {
    int i = blockIdx.x * 256 + threadIdx.x;  // 0..16383
    int k = i >> 7, n = i & 127;
    wt[n * HH + k] = f2bf(w[i]);
}

// ---------------- GEMM (f32 input): h(bf16) = in @ W ----------------
__global__ __launch_bounds__(256) void k_gemm_f(const float* __restrict__ in,
                                                const unsigned short* __restrict__ wt,
                                                unsigned short* __restrict__ h) {
    int w = threadIdx.x >> 6, lane = threadIdx.x & 63;
    int lr = lane & 15, lg = lane >> 4;
    int rowbase = (blockIdx.x * 4 + w) * 16;
    if (rowbase >= NN) return;
    int arow = rowbase + lr;
    const f32x4* ap = (const f32x4*)(in + (size_t)arow * HH + lg * 8);
    short8 a0 = cvt8(ap[0], ap[1]);
    short8 a1 = cvt8(ap[8], ap[9]);
    short8 a2 = cvt8(ap[16], ap[17]);
    short8 a3 = cvt8(ap[24], ap[25]);
    f32x4 acc[8];
    #pragma unroll
    for (int i = 0; i < 8; i++) acc[i] = (f32x4){0.f, 0.f, 0.f, 0.f};
    const unsigned short* wbase = wt + lr * HH + lg * 8;
    #pragma unroll
    for (int nc = 0; nc < 8; nc++) {
        const short8* bp = (const short8*)(wbase + nc * 16 * HH);
        short8 b0 = bp[0], b1 = bp[4], b2 = bp[8], b3 = bp[12];
        acc[nc] = __builtin_amdgcn_mfma_f32_16x16x32_bf16(a0, b0, acc[nc], 0, 0, 0);
        acc[nc] = __builtin_amdgcn_mfma_f32_16x16x32_bf16(a1, b1, acc[nc], 0, 0, 0);
        acc[nc] = __builtin_amdgcn_mfma_f32_16x16x32_bf16(a2, b2, acc[nc], 0, 0, 0);
        acc[nc] = __builtin_amdgcn_mfma_f32_16x16x32_bf16(a3, b3, acc[nc], 0, 0, 0);
    }
    int orow = rowbase + lg * 4;
    #pragma unroll
    for (int nc = 0; nc < 8; nc++) {
        #pragma unroll
        for (int j = 0; j < 4; j++) {
            h[(size_t)(orow + j) * HH + nc * 16 + lr] = f2bf(acc[nc][j]);
        }
    }
}

// ---------------- GEMM (bf16 input): h(bf16) = in @ W ----------------
__global__ __launch_bounds__(256) void k_gemm_b(const unsigned short* __restrict__ in,
                                                const unsigned short* __restrict__ wt,
                                                unsigned short* __restrict__ h) {
    int w = threadIdx.x >> 6, lane = threadIdx.x & 63;
    int lr = lane & 15, lg = lane >> 4;
    int rowbase = (blockIdx.x * 4 + w) * 16;
    if (rowbase >= NN) return;
    int arow = rowbase + lr;
    const short8* ap = (const short8*)(in + (size_t)arow * HH + lg * 8);
    short8 a0 = ap[0], a1 = ap[4], a2 = ap[8], a3 = ap[12];
    f32x4 acc[8];
    #pragma unroll
    for (int i = 0; i < 8; i++) acc[i] = (f32x4){0.f, 0.f, 0.f, 0.f};
    const unsigned short* wbase = wt + lr * HH + lg * 8;
    #pragma unroll
    for (int nc = 0; nc < 8; nc++) {
        const short8* bp = (const short8*)(wbase + nc * 16 * HH);
        short8 b0 = bp[0], b1 = bp[4], b2 = bp[8], b3 = bp[12];
        acc[nc] = __builtin_amdgcn_mfma_f32_16x16x32_bf16(a0, b0, acc[nc], 0, 0, 0);
        acc[nc] = __builtin_amdgcn_mfma_f32_16x16x32_bf16(a1, b1, acc[nc], 0, 0, 0);
        acc[nc] = __builtin_amdgcn_mfma_f32_16x16x32_bf16(a2, b2, acc[nc], 0, 0, 0);
        acc[nc] = __builtin_amdgcn_mfma_f32_16x16x32_bf16(a3, b3, acc[nc], 0, 0, 0);
    }
    int orow = rowbase + lg * 4;
    #pragma unroll
    for (int nc = 0; nc < 8; nc++) {
        #pragma unroll
        for (int j = 0; j < 4; j++) {
            h[(size_t)(orow + j) * HH + nc * 16 + lr] = f2bf(acc[nc][j]);
        }
    }
}

// ---------------- aggregation: 16 lanes/node, pre-filtered CSR section ----------------
// g[n](bf16) = bias + dinv^2*h[n] + sum_e dinv[s]*dinv[n]*h[s], optional relu
__global__ __launch_bounds__(256) void k_agg(const unsigned short* __restrict__ h,
                                             const float* __restrict__ dinv,
                                             const unsigned int* __restrict__ csr,
                                             const int* __restrict__ rp,
                                             const float* __restrict__ bias,
                                             unsigned short* __restrict__ g,
                                             int relu) {
    int tid = threadIdx.x;
    int n = blockIdx.x * 16 + (tid >> 4);   // NN % 16 == 0 -> always < NN
    int l = tid & 15;
    float di = dinv[n];
    float c = di * di;
    u32x4 hv = *(const u32x4*)(h + (size_t)n * HH + l * 8);
    float acc0 = bf2f(hv[0] & 0xffffu) * c, acc1 = bf2f(hv[0] >> 16) * c;
    float acc2 = bf2f(hv[1] & 0xffffu) * c, acc3 = bf2f(hv[1] >> 16) * c;
    float acc4 = bf2f(hv[2] & 0xffffu) * c, acc5 = bf2f(hv[2] >> 16) * c;
    float acc6 = bf2f(hv[3] & 0xffffu) * c, acc7 = bf2f(hv[3] >> 16) * c;
    int e = rp[n], end = rp[n + 1];
    for (; e + 1 < end; e += 2) {
        int s0 = (int)csr[e];
        int s1 = (int)csr[e + 1];
        float w0 = dinv[s0] * di;
        float w1 = dinv[s1] * di;
        u32x4 v0 = *(const u32x4*)(h + (size_t)s0 * HH + l * 8);
        u32x4 v1 = *(const u32x4*)(h + (size_t)s1 * HH + l * 8);
        acc0 += w0 * bf2f(v0[0] & 0xffffu); acc1 += w0 * bf2f(v0[0] >> 16);
        acc2 += w0 * bf2f(v0[1] & 0xffffu); acc3 += w0 * bf2f(v0[1] >> 16);
        acc4 += w0 * bf2f(v0[2] & 0xffffu); acc5 += w0 * bf2f(v0[2] >> 16);
        acc6 += w0 * bf2f(v0[3] & 0xffffu); acc7 += w0 * bf2f(v0[3] >> 16);
        acc0 += w1 * bf2f(v1[0] & 0xffffu); acc1 += w1 * bf2f(v1[0] >> 16);
        acc2 += w1 * bf2f(v1[1] & 0xffffu); acc3 += w1 * bf2f(v1[1] >> 16);
        acc4 += w1 * bf2f(v1[2] & 0xffffu); acc5 += w1 * bf2f(v1[2] >> 16);
        acc6 += w1 * bf2f(v1[3] & 0xffffu); acc7 += w1 * bf2f(v1[3] >> 16);
    }
    if (e < end) {
        int s0 = (int)csr[e];
        float w0 = dinv[s0] * di;
        u32x4 v0 = *(const u32x4*)(h + (size_t)s0 * HH + l * 8);
        acc0 += w0 * bf2f(v0[0] & 0xffffu); acc1 += w0 * bf2f(v0[0] >> 16);
        acc2 += w0 * bf2f(v0[1] & 0xffffu); acc3 += w0 * bf2f(v0[1] >> 16);
        acc4 += w0 * bf2f(v0[2] & 0xffffu); acc5 += w0 * bf2f(v0[2] >> 16);
        acc6 += w0 * bf2f(v0[3] & 0xffffu); acc7 += w0 * bf2f(v0[3] >> 16);
    }
    f32x4 bp0 = *(const f32x4*)(bias + l * 8);
    f32x4 bp1 = *(const f32x4*)(bias + l * 8 + 4);
    acc0 += bp0[0]; acc1 += bp0[1]; acc2 += bp0[2]; acc3 += bp0[3];
    acc4 += bp1[0]; acc5 += bp1[1]; acc6 += bp1[2]; acc7 += bp1[3];
    if (relu) {
        acc0 = fmaxf(acc0, 0.f); acc1 = fmaxf(acc1, 0.f);
        acc2 = fmaxf(acc2, 0.f); acc3 = fmaxf(acc3, 0.f);
        acc4 = fmaxf(acc4, 0.f); acc5 = fmaxf(acc5, 0.f);
        acc6 = fmaxf(acc6, 0.f); acc7 = fmaxf(acc7, 0.f);
    }
    u32x4 o;
    o[0] = (unsigned int)f2bf(acc0) | ((unsigned int)f2bf(acc1) << 16);
    o[1] = (unsigned int)f2bf(acc2) | ((unsigned int)f2bf(acc3) << 16);
    o[2] = (unsigned int)f2bf(acc4) | ((unsigned int)f2bf(acc5) << 16);
    o[3] = (unsigned int)f2bf(acc6) | ((unsigned int)f2bf(acc7) << 16);
    *(u32x4*)(g + (size_t)n * HH + l * 8) = o;
}

// ---------------- pool stage 1: per-block partial sums -> atomicAdd into sums[G][128] ----------------
__global__ __launch_bounds__(128) void k_pool_part(const unsigned short* __restrict__ g3,
                                                   const int* __restrict__ batch,
                                                   float* __restrict__ sums) {
    int t = threadIdx.x;            // feature
    int n0 = blockIdx.x * 64;
    int n1 = n0 + 64; if (n1 > NN) n1 = NN;
    int curb = batch[n0];
    float acc = 0.f;
    for (int n = n0; n < n1; n++) {
        int b = batch[n];
        if (b != curb) {
            atomicAdd(&sums[curb * HH + t], acc);
            acc = 0.f;
            curb = b;
        }
        acc += bf2f((unsigned int)g3[(size_t)n * HH + t]);
    }
    atomicAdd(&sums[curb * HH + t], acc);
}

// ---------------- pool stage 2 + head ----------------
__device__ __forceinline__ int lbound(const int* a, int n, int key) {
    int lo = 0, hi = n;
    while (lo < hi) { int mid = (lo + hi) >> 1; if (a[mid] < key) lo = mid + 1; else hi = mid; }
    return lo;
}

__global__ __launch_bounds__(128) void k_head(const float* __restrict__ sums,
                                              const int* __restrict__ batch,
                                              const float* __restrict__ Wl,
                                              const float* __restrict__ bl,
                                              float* __restrict__ out) {
    int gid = blockIdx.x;
    int t = threadIdx.x;
    int lo = lbound(batch, NN, gid);
    int hi = lbound(batch, NN, gid + 1);
    float cnt = (float)(hi - lo);
    if (cnt < 1.f) cnt = 1.f;
    float prod = (sums[gid * HH + t] / cnt) * Wl[t];
    __shared__ float sm[128];
    sm[t] = prod;
    __syncthreads();
    for (int off = 64; off > 0; off >>= 1) {
        if (t < off) sm[t] += sm[t + off];
        __syncthreads();
    }
    if (t == 0) out[gid] = sm[0] + bl[0];
}

// ---------------- launcher ----------------
extern "C" void kernel_launch(void* const* d_in, const int* in_sizes, int n_in,
                              void* d_out, int out_size, void* d_ws, size_t ws_size,
                              hipStream_t stream) {
    const float* x    = (const float*)d_in[0];
    const int*   ei   = (const int*)d_in[1];
    const int*   mask = (const int*)d_in[2];
    const int*   batch= (const int*)d_in[3];
    const float* W1   = (const float*)d_in[4];
    const float* b1   = (const float*)d_in[5];
    const float* W2   = (const float*)d_in[6];
    const float* b2   = (const float*)d_in[7];
    const float* W3   = (const float*)d_in[8];
    const float* b3   = (const float*)d_in[9];
    const float* Wl   = (const float*)d_in[10];
    const float* bl   = (const float*)d_in[11];
    float* out = (float*)d_out;

    char* ws = (char*)d_ws;
    unsigned short* g = (unsigned short*)(ws + 0);          // N*128 bf16 = 12,800,000
    unsigned short* h = (unsigned short*)(ws + 12800000);   // N*128 bf16 = 12,800,000
    unsigned short* wt1 = (unsigned short*)(ws + 25600000); // 3 x 128*128 bf16 = 98,304
    unsigned short* wt2 = wt1 + 16384;
    unsigned short* wt3 = wt2 + 16384;
    int* deg    = (int*)(ws + 25698304);                    // 3*NPAD int -> dinv f32 in place
    int* rpAll  = (int*)(ws + 26300416);                    // 3*NPAD int
    int* curAll = (int*)(ws + 26902528);                    // 3*NPAD int; reused as sums after fill
    int* btot   = (int*)(ws + 27504640);                    // 1024 int
    int* boff   = (int*)(ws + 27508736);                    // 1024 int
    unsigned int* csr = (unsigned int*)(ws + 27512832);     // up to 1.2M uints = 4,800,000
    float* sums = (float*)curAll;                           // 64*128 f32
    // total = 32,312,832 bytes

    float* dinv1 = (float*)deg;
    float* dinv2 = dinv1 + NPAD;
    float* dinv3 = dinv2 + NPAD;

    hipMemsetAsync(deg, 0, (size_t)3 * NPAD * sizeof(int), stream);

    dim3 b256(256);
    k_deg<<<dim3((EE + 255) / 256), b256, 0, stream>>>(ei, mask, deg);
    k_scan1<<<dim3(NBLK3), b256, 0, stream>>>(deg, btot);
    k_scan2<<<dim3(1), dim3(1024), 0, stream>>>(btot, boff);
    k_scan3<<<dim3(NBLK3), b256, 0, stream>>>(deg, boff, rpAll, curAll);
    k_dinv<<<dim3((NN + 255) / 256), b256, 0, stream>>>(deg);
    k_fill3<<<dim3((EE + 255) / 256), b256, 0, stream>>>(ei, mask, curAll, csr);
    // curAll dead; reuse as pooled sums
    hipMemsetAsync(sums, 0, (size_t)GG * HH * sizeof(float), stream);

    k_wt<<<dim3(64), b256, 0, stream>>>(W1, wt1);
    k_wt<<<dim3(64), b256, 0, stream>>>(W2, wt2);
    k_wt<<<dim3(64), b256, 0, stream>>>(W3, wt3);

    dim3 ggrid((NN + 63) / 64);   // 782 blocks (gemm)
    dim3 agrid(NN / 16);          // 3125 blocks (agg), NN % 16 == 0

    // layer 1: all edges (section 0)
    k_gemm_f<<<ggrid, b256, 0, stream>>>(x, wt1, h);
    k_agg<<<agrid, b256, 0, stream>>>(h, dinv1, csr, rpAll, b1, g, 1);
    // layer 2: mask==1 (section 1)
    k_gemm_b<<<ggrid, b256, 0, stream>>>(g, wt2, h);
    k_agg<<<agrid, b256, 0, stream>>>(h, dinv2, csr, rpAll + NPAD, b2, g, 1);
    // layer 3: mask==2 (section 2), no relu
    k_gemm_b<<<ggrid, b256, 0, stream>>>(g, wt3, h);
    k_agg<<<agrid, b256, 0, stream>>>(h, dinv3, csr, rpAll + 2 * NPAD, b3, g, 0);

    k_pool_part<<<dim3((NN + 63) / 64), dim3(128), 0, stream>>>(g, batch, sums);
    k_head<<<dim3(GG), dim3(128), 0, stream>>>(sums, batch, Wl, bl, out);
}